// Round 2
// baseline (396.573 us; speedup 1.0000x reference)
//
#include <hip/hip_runtime.h>
#include <hip/hip_bf16.h>

#define NROWS 100000
#define FT 256
#define NC 16

// ws layout (in floats)
#define WS_COEF 0      // 256 floats
#define WS_SUMS 256    // 4096 floats (zeroed per launch)
#define WS_CNTS 4352   // 16 floats   (zeroed per launch)
#define WS_AVEB 4368   // 2048 floats = 4096 bf16 (ave, class-major [c][f])
#define WS_NRM  6416   // 16 floats (ave norms)
// total 6432 floats = 25728 bytes

typedef float f32x4 __attribute__((ext_vector_type(4)));
typedef short bf16x8 __attribute__((ext_vector_type(8)));

static __device__ __forceinline__ float bfbits2f(unsigned int u16) {
    union { unsigned int i; float f; } v; v.i = u16 << 16; return v.f;
}
static __device__ __forceinline__ unsigned short f2bf(float f) {
    union { float f; unsigned int i; } v; v.f = f;
    unsigned int u = v.i;
    u += 0x7fffu + ((u >> 16) & 1u);   // RNE
    return (unsigned short)(u >> 16);
}

// K0: coef[f] = wf0 * (1 + elu(w_wp . prompt))[f] + wf1 * w_dp[f]
__global__ void k_prep(const float* __restrict__ p1,
                       const float* __restrict__ p2,
                       const float* __restrict__ p3,
                       const float* __restrict__ wwp,
                       const float* __restrict__ wwf,
                       const float* __restrict__ wdp,
                       float* __restrict__ ws)
{
    int f = threadIdx.x;
    float z = wwp[0] * p1[f] + wwp[1] * p2[f] + wwp[2] * p3[f];
    float weight = (z > 0.f) ? (1.f + z) : __expf(z);   // 1 + elu(z)
    ws[WS_COEF + f] = wwf[0] * weight + wwf[1] * wdp[f];
}

// K1: per-class sums of rawret + counts. 32 lanes/row, 8 fp32 per lane.
// LDS swizzle: value i of lane m stored at 8m + ((i + (m>>2)) & 7) so all
// 32 lanes of a row hit 32 distinct banks (2 lanes/bank per wave64 = free).
__global__ __launch_bounds__(1024) void k_accum(
    const float* __restrict__ seq,
    const float* __restrict__ seq1,
    const int* __restrict__ labels,
    const float* __restrict__ a4p,
    float* __restrict__ ws)
{
    __shared__ float lsum[NC * FT];
    __shared__ float lcnt[NC];
    const int tid = threadIdx.x;
    for (int i = tid; i < NC * FT; i += 1024) lsum[i] = 0.f;
    if (tid < NC) lcnt[tid] = 0.f;
    __syncthreads();

    const int rr = tid >> 5;      // row-in-block 0..31
    const int m  = tid & 31;      // lane-in-row
    const int f0 = m * 8;
    const int mh = m >> 2;
    int off[8];
#pragma unroll
    for (int i = 0; i < 8; ++i) off[i] = (i + mh) & 7;

    float cof[8];
    {
        const float4 c0 = *(const float4*)(ws + WS_COEF + f0);
        const float4 c1 = *(const float4*)(ws + WS_COEF + f0 + 4);
        cof[0]=c0.x; cof[1]=c0.y; cof[2]=c0.z; cof[3]=c0.w;
        cof[4]=c1.x; cof[5]=c1.y; cof[6]=c1.z; cof[7]=c1.w;
    }
    const float a4v = a4p[0];

    for (int row = blockIdx.x * 32 + rr; row < NROWS; row += gridDim.x * 32) {
        const int lab = labels[row];
        const float4 sa  = *(const float4*)(seq  + row * FT + f0);
        const float4 sb  = *(const float4*)(seq  + row * FT + f0 + 4);
        const float4 ta  = *(const float4*)(seq1 + row * FT + f0);
        const float4 tb  = *(const float4*)(seq1 + row * FT + f0 + 4);
        const float s[8]  = {sa.x,sa.y,sa.z,sa.w, sb.x,sb.y,sb.z,sb.w};
        const float t[8]  = {ta.x,ta.y,ta.z,ta.w, tb.x,tb.y,tb.z,tb.w};
        float v[8];
#pragma unroll
        for (int i = 0; i < 8; ++i) {
            float u = cof[i] * s[i];
            float r = (u > 0.f) ? u : (__expf(u) - 1.f);   // elu
            v[i] = r + a4v * t[i];
        }
        float* base = lsum + lab * FT + f0;
#pragma unroll
        for (int i = 0; i < 8; ++i) atomicAdd(base + off[i], v[i]);
        if (m == 0) atomicAdd(&lcnt[lab], 1.f);
    }
    __syncthreads();

    // flush (unswizzle): pos p=8m+r holds feature f=8m+((r-(m>>2))&7)
    for (int idx = tid; idx < NC * FT; idx += 1024) {
        int p  = idx & 255;
        int mm = p >> 3;
        int r  = p & 7;
        int f  = (p & ~7) | ((r - (mm >> 2)) & 7);
        atomicAdd(ws + WS_SUMS + (idx & ~255) + f, lsum[idx]);
    }
    if (tid < NC) atomicAdd(ws + WS_CNTS + tid, lcnt[tid]);
}

// K1.5: ave = sums / max(cnt,1) -> bf16; ave norms (of bf16-rounded ave)
__global__ void k_final(float* __restrict__ ws)
{
    __shared__ float nacc[NC];
    const int f = threadIdx.x;
    if (f < NC) nacc[f] = 0.f;
    __syncthreads();
    unsigned short* aveb = (unsigned short*)(ws + WS_AVEB);
#pragma unroll
    for (int c = 0; c < NC; ++c) {
        float cnt = ws[WS_CNTS + c];
        float a = ws[WS_SUMS + c * FT + f] / fmaxf(cnt, 1.f);
        unsigned short ab = f2bf(a);
        aveb[c * FT + f] = ab;
        float af = bfbits2f(ab);
        atomicAdd(&nacc[c], af * af);
    }
    __syncthreads();
    if (f < NC) ws[WS_NRM + f] = sqrtf(nacc[f]);
}

// K2: per 16-row tile: recompute rawret -> bf16 A-frags,
//   accC += A . aveT   (mfma 16x16x32 bf16)
//   accS += A . A^T    (same frag both operands; diag = row self-dots)
// then cosine + softmax over 16 classes via width-16 shuffles.
__global__ __launch_bounds__(256) void k_out(
    const float* __restrict__ seq,
    const float* __restrict__ seq1,
    const float* __restrict__ a4p,
    const float* __restrict__ ws,
    float* __restrict__ out)
{
    __shared__ __align__(16) float scoef[FT];
    const int tid = threadIdx.x;
    for (int i = tid; i < FT; i += 256) scoef[i] = ws[WS_COEF + i];
    __syncthreads();

    const int lane = tid & 63;
    const int wv   = tid >> 6;
    const int c = lane & 15;   // class (B col) == A row index m
    const int g = lane >> 4;   // k-quad

    const unsigned short* aveb = (const unsigned short*)(ws + WS_AVEB);
    bf16x8 bfrag[8];
#pragma unroll
    for (int kc = 0; kc < 8; ++kc)
        bfrag[kc] = *(const bf16x8*)(aveb + c * FT + kc * 32 + g * 8);
    const float na  = ws[WS_NRM + c];
    const float a4v = a4p[0];

    const int ntiles = NROWS / 16;   // 6250 exact
    for (int tile = blockIdx.x * 4 + wv; tile < ntiles; tile += gridDim.x * 4) {
        const int rowbase = tile * 16;
        const int arow = rowbase + c;     // A row m = lane&15
        f32x4 accC = {0.f, 0.f, 0.f, 0.f};
        f32x4 accS = {0.f, 0.f, 0.f, 0.f};
#pragma unroll
        for (int kc = 0; kc < 8; ++kc) {
            const int k0 = kc * 32 + g * 8;
            const float4 sa = *(const float4*)(seq  + arow * FT + k0);
            const float4 sb = *(const float4*)(seq  + arow * FT + k0 + 4);
            const float4 ta = *(const float4*)(seq1 + arow * FT + k0);
            const float4 tb = *(const float4*)(seq1 + arow * FT + k0 + 4);
            const float4 c0 = *(const float4*)(scoef + k0);
            const float4 c1 = *(const float4*)(scoef + k0 + 4);
            const float s[8]  = {sa.x,sa.y,sa.z,sa.w, sb.x,sb.y,sb.z,sb.w};
            const float t[8]  = {ta.x,ta.y,ta.z,ta.w, tb.x,tb.y,tb.z,tb.w};
            const float cf[8] = {c0.x,c0.y,c0.z,c0.w, c1.x,c1.y,c1.z,c1.w};
            bf16x8 afrag;
#pragma unroll
            for (int i = 0; i < 8; ++i) {
                float u = cf[i] * s[i];
                float r = (u > 0.f) ? u : (__expf(u) - 1.f);
                afrag[i] = (short)f2bf(r + a4v * t[i]);
            }
            accC = __builtin_amdgcn_mfma_f32_16x16x32_bf16(afrag, bfrag[kc], accC, 0, 0, 0);
            accS = __builtin_amdgcn_mfma_f32_16x16x32_bf16(afrag, afrag,     accS, 0, 0, 0);
        }
        // C/D layout: col=lane&15, row=g*4+reg.
        // self-dot of row r sits at lane (r>>2)*16 + (r&15)... = 20g+q, reg q.
#pragma unroll
        for (int q = 0; q < 4; ++q) {
            const float sd = __shfl(accS[q], g * 20 + q, 64);
            const float nr = sqrtf(fmaxf(sd, 0.f));
            const float denom = fmaxf(nr * na, 1e-8f);
            float cosv = accC[q] / denom;
            float mx = cosv;
#pragma unroll
            for (int o = 1; o < 16; o <<= 1) mx = fmaxf(mx, __shfl_xor(mx, o, 16));
            const float e = __expf(cosv - mx);
            float s = e;
#pragma unroll
            for (int o = 1; o < 16; o <<= 1) s += __shfl_xor(s, o, 16);
            out[(rowbase + g * 4 + q) * NC + c] = e / s;
        }
    }
}

extern "C" void kernel_launch(void* const* d_in, const int* in_sizes, int n_in,
                              void* d_out, int out_size, void* d_ws, size_t ws_size,
                              hipStream_t stream)
{
    const float* seq  = (const float*)d_in[0];
    const float* seq1 = (const float*)d_in[1];
    const int*   lab  = (const int*)d_in[2];
    const float* p1   = (const float*)d_in[3];
    const float* p2   = (const float*)d_in[4];
    const float* p3   = (const float*)d_in[5];
    const float* wwp  = (const float*)d_in[6];
    const float* wwf  = (const float*)d_in[7];
    const float* wdp  = (const float*)d_in[8];
    const float* a4   = (const float*)d_in[9];
    float* ws  = (float*)d_ws;
    float* out = (float*)d_out;

    // zero the atomic accumulators (ws is poisoned 0xAA before every launch)
    hipMemsetAsync((char*)d_ws + WS_SUMS * sizeof(float), 0,
                   (NC * FT + NC) * sizeof(float), stream);

    k_prep <<<1,   256, 0, stream>>>(p1, p2, p3, wwp, wwf, wdp, ws);
    k_accum<<<512, 1024, 0, stream>>>(seq, seq1, lab, a4, ws);
    k_final<<<1,   256, 0, stream>>>(ws);
    k_out  <<<784, 256, 0, stream>>>(seq, seq1, a4, ws, out);
}

// Round 3
// 327.577 us; speedup vs baseline: 1.2106x; 1.2106x over previous
//
#include <hip/hip_runtime.h>
#include <hip/hip_bf16.h>

#define NROWS 100000
#define FT 256
#define NC 16

// fixed-point scale for class-sum accumulation
#define FPSCALE 1048576.0f      // 2^20
#define FPINV   (1.0f / 1048576.0f)

// ws layout (in 4-byte words)
#define WS_COEF 0      // 256 floats
#define WS_SUMS 256    // 4096 int32 (zeroed per launch)
#define WS_CNTS 4352   // 16 int32   (zeroed per launch)
#define WS_AVEB 4368   // 2048 words = 4096 bf16 (ave, class-major [c][f])
#define WS_NRM  6416   // 16 floats (ave norms)
// total 6432 words = 25728 bytes

typedef float f32x4 __attribute__((ext_vector_type(4)));
typedef short bf16x8 __attribute__((ext_vector_type(8)));

static __device__ __forceinline__ float bfbits2f(unsigned int u16) {
    union { unsigned int i; float f; } v; v.i = u16 << 16; return v.f;
}
static __device__ __forceinline__ unsigned short f2bf(float f) {
    union { float f; unsigned int i; } v; v.f = f;
    unsigned int u = v.i;
    u += 0x7fffu + ((u >> 16) & 1u);   // RNE
    return (unsigned short)(u >> 16);
}

// K0: coef[f] = wf0 * (1 + elu(w_wp . prompt))[f] + wf1 * w_dp[f]
__global__ void k_prep(const float* __restrict__ p1,
                       const float* __restrict__ p2,
                       const float* __restrict__ p3,
                       const float* __restrict__ wwp,
                       const float* __restrict__ wwf,
                       const float* __restrict__ wdp,
                       float* __restrict__ ws)
{
    int f = threadIdx.x;
    float z = wwp[0] * p1[f] + wwp[1] * p2[f] + wwp[2] * p3[f];
    float weight = (z > 0.f) ? (1.f + z) : __expf(z);   // 1 + elu(z)
    ws[WS_COEF + f] = wwf[0] * weight + wwf[1] * wdp[f];
}

// K1: per-class sums of rawret + counts, fixed-point int32 (all atomics are
// native int adds: ds_add_u32 in LDS, global_atomic_add on flush — no CAS
// loops, unlike fp32 atomicAdd). 32 lanes/row, 8 fp32 features per lane.
// LDS swizzle: value i of lane m stored at 8m + ((i + (m>>2)) & 7) so all
// 32 lanes of a row hit 32 distinct banks (2 lanes/bank per wave64 = free).
__global__ __launch_bounds__(1024) void k_accum(
    const float* __restrict__ seq,
    const float* __restrict__ seq1,
    const int* __restrict__ labels,
    const float* __restrict__ a4p,
    float* __restrict__ ws)
{
    __shared__ int lsum[NC * FT];
    __shared__ int lcnt[NC];
    const int tid = threadIdx.x;
    for (int i = tid; i < NC * FT; i += 1024) lsum[i] = 0;
    if (tid < NC) lcnt[tid] = 0;
    __syncthreads();

    const int rr = tid >> 5;      // row-in-block 0..31
    const int m  = tid & 31;      // lane-in-row
    const int f0 = m * 8;
    const int mh = m >> 2;
    int off[8];
#pragma unroll
    for (int i = 0; i < 8; ++i) off[i] = (i + mh) & 7;

    float cof[8];
    {
        const float4 c0 = *(const float4*)(ws + WS_COEF + f0);
        const float4 c1 = *(const float4*)(ws + WS_COEF + f0 + 4);
        cof[0]=c0.x; cof[1]=c0.y; cof[2]=c0.z; cof[3]=c0.w;
        cof[4]=c1.x; cof[5]=c1.y; cof[6]=c1.z; cof[7]=c1.w;
    }
    const float a4v = a4p[0];

    for (int row = blockIdx.x * 32 + rr; row < NROWS; row += gridDim.x * 32) {
        const int lab = labels[row];
        const float4 sa  = *(const float4*)(seq  + row * FT + f0);
        const float4 sb  = *(const float4*)(seq  + row * FT + f0 + 4);
        const float4 ta  = *(const float4*)(seq1 + row * FT + f0);
        const float4 tb  = *(const float4*)(seq1 + row * FT + f0 + 4);
        const float s[8]  = {sa.x,sa.y,sa.z,sa.w, sb.x,sb.y,sb.z,sb.w};
        const float t[8]  = {ta.x,ta.y,ta.z,ta.w, tb.x,tb.y,tb.z,tb.w};
        int* base = lsum + lab * FT + f0;
#pragma unroll
        for (int i = 0; i < 8; ++i) {
            float u = cof[i] * s[i];
            float r = (u > 0.f) ? u : (__expf(u) - 1.f);   // elu
            int iv = __float2int_rn((r + a4v * t[i]) * FPSCALE);
            atomicAdd(base + off[i], iv);
        }
        if (m == 0) atomicAdd(&lcnt[lab], 1);
    }
    __syncthreads();

    // flush (unswizzle): pos p=8m+r holds feature f=8m+((r-(m>>2))&7)
    int* gsum = (int*)(ws + WS_SUMS);
    for (int idx = tid; idx < NC * FT; idx += 1024) {
        int p  = idx & 255;
        int mm = p >> 3;
        int r  = p & 7;
        int f  = (p & ~7) | ((r - (mm >> 2)) & 7);
        atomicAdd(gsum + (idx & ~255) + f, lsum[idx]);
    }
    if (tid < NC) atomicAdd((int*)(ws + WS_CNTS) + tid, lcnt[tid]);
}

// K1.5: ave = sums / max(cnt,1) -> bf16; ave norms (of bf16-rounded ave)
__global__ void k_final(float* __restrict__ ws)
{
    __shared__ float nacc[NC];
    const int f = threadIdx.x;
    if (f < NC) nacc[f] = 0.f;
    __syncthreads();
    const int* gsum = (const int*)(ws + WS_SUMS);
    const int* gcnt = (const int*)(ws + WS_CNTS);
    unsigned short* aveb = (unsigned short*)(ws + WS_AVEB);
#pragma unroll
    for (int c = 0; c < NC; ++c) {
        float cnt = (float)gcnt[c];
        float a = ((float)gsum[c * FT + f] * FPINV) / fmaxf(cnt, 1.f);
        unsigned short ab = f2bf(a);
        aveb[c * FT + f] = ab;
        float af = bfbits2f(ab);
        atomicAdd(&nacc[c], af * af);   // LDS fp32, 256 lanes x 16 addrs, one-shot
    }
    __syncthreads();
    if (f < NC) ws[WS_NRM + f] = sqrtf(nacc[f]);
}

// K2: per 16-row tile: recompute rawret -> bf16 A-frags,
//   accC += A . aveT   (mfma 16x16x32 bf16)
//   accS += A . A^T    (same frag both operands; diag = row self-dots)
// then cosine + softmax over 16 classes via width-16 shuffles.
__global__ __launch_bounds__(256) void k_out(
    const float* __restrict__ seq,
    const float* __restrict__ seq1,
    const float* __restrict__ a4p,
    const float* __restrict__ ws,
    float* __restrict__ out)
{
    __shared__ __align__(16) float scoef[FT];
    const int tid = threadIdx.x;
    for (int i = tid; i < FT; i += 256) scoef[i] = ws[WS_COEF + i];
    __syncthreads();

    const int lane = tid & 63;
    const int wv   = tid >> 6;
    const int c = lane & 15;   // class (B col) == A row index m
    const int g = lane >> 4;   // k-quad

    const unsigned short* aveb = (const unsigned short*)(ws + WS_AVEB);
    bf16x8 bfrag[8];
#pragma unroll
    for (int kc = 0; kc < 8; ++kc)
        bfrag[kc] = *(const bf16x8*)(aveb + c * FT + kc * 32 + g * 8);
    const float na  = ws[WS_NRM + c];
    const float a4v = a4p[0];

    const int ntiles = NROWS / 16;   // 6250 exact
    for (int tile = blockIdx.x * 4 + wv; tile < ntiles; tile += gridDim.x * 4) {
        const int rowbase = tile * 16;
        const int arow = rowbase + c;     // A row m = lane&15
        f32x4 accC = {0.f, 0.f, 0.f, 0.f};
        f32x4 accS = {0.f, 0.f, 0.f, 0.f};
#pragma unroll
        for (int kc = 0; kc < 8; ++kc) {
            const int k0 = kc * 32 + g * 8;
            const float4 sa = *(const float4*)(seq  + arow * FT + k0);
            const float4 sb = *(const float4*)(seq  + arow * FT + k0 + 4);
            const float4 ta = *(const float4*)(seq1 + arow * FT + k0);
            const float4 tb = *(const float4*)(seq1 + arow * FT + k0 + 4);
            const float4 c0 = *(const float4*)(scoef + k0);
            const float4 c1 = *(const float4*)(scoef + k0 + 4);
            const float s[8]  = {sa.x,sa.y,sa.z,sa.w, sb.x,sb.y,sb.z,sb.w};
            const float t[8]  = {ta.x,ta.y,ta.z,ta.w, tb.x,tb.y,tb.z,tb.w};
            const float cf[8] = {c0.x,c0.y,c0.z,c0.w, c1.x,c1.y,c1.z,c1.w};
            bf16x8 afrag;
#pragma unroll
            for (int i = 0; i < 8; ++i) {
                float u = cf[i] * s[i];
                float r = (u > 0.f) ? u : (__expf(u) - 1.f);
                afrag[i] = (short)f2bf(r + a4v * t[i]);
            }
            accC = __builtin_amdgcn_mfma_f32_16x16x32_bf16(afrag, bfrag[kc], accC, 0, 0, 0);
            accS = __builtin_amdgcn_mfma_f32_16x16x32_bf16(afrag, afrag,     accS, 0, 0, 0);
        }
        // C/D layout: col=lane&15, row=g*4+reg.
        // self-dot of row r sits at lane 20g+q (for r = 4g+q), reg q.
#pragma unroll
        for (int q = 0; q < 4; ++q) {
            const float sd = __shfl(accS[q], g * 20 + q, 64);
            const float nr = sqrtf(fmaxf(sd, 0.f));
            const float denom = fmaxf(nr * na, 1e-8f);
            float cosv = accC[q] / denom;
            float mx = cosv;
#pragma unroll
            for (int o = 1; o < 16; o <<= 1) mx = fmaxf(mx, __shfl_xor(mx, o, 16));
            const float e = __expf(cosv - mx);
            float s = e;
#pragma unroll
            for (int o = 1; o < 16; o <<= 1) s += __shfl_xor(s, o, 16);
            out[(rowbase + g * 4 + q) * NC + c] = e / s;
        }
    }
}

extern "C" void kernel_launch(void* const* d_in, const int* in_sizes, int n_in,
                              void* d_out, int out_size, void* d_ws, size_t ws_size,
                              hipStream_t stream)
{
    const float* seq  = (const float*)d_in[0];
    const float* seq1 = (const float*)d_in[1];
    const int*   lab  = (const int*)d_in[2];
    const float* p1   = (const float*)d_in[3];
    const float* p2   = (const float*)d_in[4];
    const float* p3   = (const float*)d_in[5];
    const float* wwp  = (const float*)d_in[6];
    const float* wwf  = (const float*)d_in[7];
    const float* wdp  = (const float*)d_in[8];
    const float* a4   = (const float*)d_in[9];
    float* ws  = (float*)d_ws;
    float* out = (float*)d_out;

    // zero the int accumulators (ws is poisoned 0xAA before every launch)
    hipMemsetAsync((char*)d_ws + WS_SUMS * sizeof(int), 0,
                   (NC * FT + NC) * sizeof(int), stream);

    k_prep <<<1,    256, 0, stream>>>(p1, p2, p3, wwp, wwf, wdp, ws);
    k_accum<<<512, 1024, 0, stream>>>(seq, seq1, lab, a4, ws);
    k_final<<<1,    256, 0, stream>>>(ws);
    k_out  <<<1568, 256, 0, stream>>>(seq, seq1, a4, ws, out);
}

// Round 4
// 292.339 us; speedup vs baseline: 1.3566x; 1.1205x over previous
//
#include <hip/hip_runtime.h>
#include <hip/hip_bf16.h>

#define NROWS 100000
#define FT 256
#define NC 16
#define NBLK 512          // k_accum blocks (cached path)

// fixed-point scale for class-sum accumulation
#define FPSCALE 1048576.0f      // 2^20
#define FPINV   (1.0f / 1048576.0f)

// ---------------- cached-path ws layout (4-byte words) ----------------
#define CW_COEF 0                      // 256 floats
#define CW_AVEB 256                    // 2048 words = 4096 bf16 ave [c][f]
#define CW_NRM  2304                   // 16 floats
#define CW_PCNT 2320                   // NBLK*16 ints
#define CW_PART (2320 + NBLK*16)       // NBLK*4096 ints
#define CW_RAWB (CW_PART + NBLK*4096)  // NROWS*FT bf16 = 12.8M words
#define CW_TOTAL (CW_RAWB + (NROWS*FT)/2)
#define CACHED_NEED_BYTES ((size_t)CW_TOTAL * 4)

// ---------------- fallback ws layout (R3, 4-byte words) ----------------
#define WS_COEF 0
#define WS_SUMS 256
#define WS_CNTS 4352
#define WS_AVEB 4368
#define WS_NRM  6416

typedef float f32x4 __attribute__((ext_vector_type(4)));
typedef short bf16x8 __attribute__((ext_vector_type(8)));

static __device__ __forceinline__ float bfbits2f(unsigned int u16) {
    union { unsigned int i; float f; } v; v.i = u16 << 16; return v.f;
}
static __device__ __forceinline__ unsigned short f2bf(float f) {
    union { float f; unsigned int i; } v; v.f = f;
    unsigned int u = v.i;
    u += 0x7fffu + ((u >> 16) & 1u);   // RNE
    return (unsigned short)(u >> 16);
}

// K0: coef[f] = wf0 * (1 + elu(w_wp . prompt))[f] + wf1 * w_dp[f]
// (coef written at word 0 in both layouts)
__global__ void k_prep(const float* __restrict__ p1,
                       const float* __restrict__ p2,
                       const float* __restrict__ p3,
                       const float* __restrict__ wwp,
                       const float* __restrict__ wwf,
                       const float* __restrict__ wdp,
                       float* __restrict__ ws)
{
    int f = threadIdx.x;
    float z = wwp[0] * p1[f] + wwp[1] * p2[f] + wwp[2] * p3[f];
    float weight = (z > 0.f) ? (1.f + z) : __expf(z);   // 1 + elu(z)
    ws[CW_COEF + f] = wwf[0] * weight + wwf[1] * wdp[f];
}

// ======================= cached path =======================

// K1c: compute rawret, cache it as bf16, accumulate per-class fixed-point
// sums in LDS (native ds_add), then write block-private partials
// (NO global atomics). 32 lanes/row, 8 features/lane.
__global__ __launch_bounds__(1024) void k_accum_c(
    const float* __restrict__ seq,
    const float* __restrict__ seq1,
    const int* __restrict__ labels,
    const float* __restrict__ a4p,
    float* __restrict__ ws)
{
    __shared__ int lsum[NC * FT];
    __shared__ int lcnt[NC];
    const int tid = threadIdx.x;
    for (int i = tid; i < NC * FT; i += 1024) lsum[i] = 0;
    if (tid < NC) lcnt[tid] = 0;
    __syncthreads();

    const int rr = tid >> 5;      // row-in-block 0..31
    const int m  = tid & 31;      // lane-in-row
    const int f0 = m * 8;
    const int mh = m >> 2;
    int off[8];
#pragma unroll
    for (int i = 0; i < 8; ++i) off[i] = (i + mh) & 7;

    float cof[8];
    {
        const float4 c0 = *(const float4*)(ws + CW_COEF + f0);
        const float4 c1 = *(const float4*)(ws + CW_COEF + f0 + 4);
        cof[0]=c0.x; cof[1]=c0.y; cof[2]=c0.z; cof[3]=c0.w;
        cof[4]=c1.x; cof[5]=c1.y; cof[6]=c1.z; cof[7]=c1.w;
    }
    const float a4v = a4p[0];
    unsigned int* rawb = (unsigned int*)(ws + CW_RAWB);

    for (int row = blockIdx.x * 32 + rr; row < NROWS; row += gridDim.x * 32) {
        const int lab = labels[row];
        const float4 sa  = *(const float4*)(seq  + row * FT + f0);
        const float4 sb  = *(const float4*)(seq  + row * FT + f0 + 4);
        const float4 ta  = *(const float4*)(seq1 + row * FT + f0);
        const float4 tb  = *(const float4*)(seq1 + row * FT + f0 + 4);
        const float s[8]  = {sa.x,sa.y,sa.z,sa.w, sb.x,sb.y,sb.z,sb.w};
        const float t[8]  = {ta.x,ta.y,ta.z,ta.w, tb.x,tb.y,tb.z,tb.w};
        int* base = lsum + lab * FT + f0;
        unsigned short vb[8];
#pragma unroll
        for (int i = 0; i < 8; ++i) {
            float u = cof[i] * s[i];
            float r = (u > 0.f) ? u : (__expf(u) - 1.f);   // elu
            float v = r + a4v * t[i];
            vb[i] = f2bf(v);
            atomicAdd(base + off[i], __float2int_rn(v * FPSCALE));
        }
        uint4 pk;
        pk.x = (unsigned int)vb[0] | ((unsigned int)vb[1] << 16);
        pk.y = (unsigned int)vb[2] | ((unsigned int)vb[3] << 16);
        pk.z = (unsigned int)vb[4] | ((unsigned int)vb[5] << 16);
        pk.w = (unsigned int)vb[6] | ((unsigned int)vb[7] << 16);
        *(uint4*)(rawb + (row * FT + f0) / 2) = pk;
        if (m == 0) atomicAdd(&lcnt[lab], 1);
    }
    __syncthreads();

    // flush block-private partials (unswizzle): pos p=8m+r holds
    // feature f=8m+((r-(m>>2))&7). partial layout [block][c][f].
    int* gpart = (int*)(ws + CW_PART) + blockIdx.x * (NC * FT);
    for (int idx = tid; idx < NC * FT; idx += 1024) {
        int p  = idx & 255;
        int mm = p >> 3;
        int r  = p & 7;
        int f  = (p & ~7) | ((r - (mm >> 2)) & 7);
        gpart[(idx & ~255) + f] = lsum[idx];
    }
    if (tid < NC) ((int*)(ws + CW_PCNT))[blockIdx.x * NC + tid] = lcnt[tid];
}

// K1.5c: one block per class: reduce NBLK partials -> ave bf16 + norm
__global__ __launch_bounds__(256) void k_reduce(float* __restrict__ ws)
{
    __shared__ float red[256];
    const int c = blockIdx.x;
    const int f = threadIdx.x;

    // count for this class
    const int* pcnt = (const int*)(ws + CW_PCNT);
    int cacc = 0;
    for (int p = f; p < NBLK; p += 256) cacc += pcnt[p * NC + c];
    red[f] = (float)cacc;
    __syncthreads();
#pragma unroll
    for (int s = 128; s > 0; s >>= 1) {
        if (f < s) red[f] += red[f + s];
        __syncthreads();
    }
    const float cnt = red[0];
    __syncthreads();

    // feature sum for (c, f)
    const int* gpart = (const int*)(ws + CW_PART);
    long long isum = 0;
    for (int p = 0; p < NBLK; ++p)
        isum += (long long)gpart[p * (NC * FT) + c * FT + f];
    float a = ((float)isum * FPINV) / fmaxf(cnt, 1.f);
    unsigned short ab = f2bf(a);
    ((unsigned short*)(ws + CW_AVEB))[c * FT + f] = ab;
    float af = bfbits2f(ab);

    red[f] = af * af;
    __syncthreads();
#pragma unroll
    for (int s = 128; s > 0; s >>= 1) {
        if (f < s) red[f] += red[f + s];
        __syncthreads();
    }
    if (f == 0) ws[CW_NRM + c] = sqrtf(red[0]);
}

// K2c: per 16-row tile, load cached bf16 rawret fragments,
//   accC += A . aveT ; accS += A . A^T (diag = self-dots)
// then cosine + softmax via width-16 shuffles.
__global__ __launch_bounds__(256) void k_out_c(
    const float* __restrict__ ws,
    float* __restrict__ out)
{
    const int tid = threadIdx.x;
    const int lane = tid & 63;
    const int wv   = tid >> 6;
    const int c = lane & 15;   // class (B col) == A row index m
    const int g = lane >> 4;   // k-quad

    const unsigned short* aveb = (const unsigned short*)(ws + CW_AVEB);
    const unsigned short* rawb = (const unsigned short*)(ws + CW_RAWB);
    bf16x8 bfrag[8];
#pragma unroll
    for (int kc = 0; kc < 8; ++kc)
        bfrag[kc] = *(const bf16x8*)(aveb + c * FT + kc * 32 + g * 8);
    const float na = ws[CW_NRM + c];

    const int ntiles = NROWS / 16;   // 6250 exact
    for (int tile = blockIdx.x * 4 + wv; tile < ntiles; tile += gridDim.x * 4) {
        const int rowbase = tile * 16;
        const int arow = rowbase + c;     // A row m = lane&15
        f32x4 accC = {0.f, 0.f, 0.f, 0.f};
        f32x4 accS = {0.f, 0.f, 0.f, 0.f};
#pragma unroll
        for (int kc = 0; kc < 8; ++kc) {
            bf16x8 afrag = *(const bf16x8*)(rawb + arow * FT + kc * 32 + g * 8);
            accC = __builtin_amdgcn_mfma_f32_16x16x32_bf16(afrag, bfrag[kc], accC, 0, 0, 0);
            accS = __builtin_amdgcn_mfma_f32_16x16x32_bf16(afrag, afrag,     accS, 0, 0, 0);
        }
        // C/D layout: col=lane&15, row=g*4+reg; self-dot of row r=4g+q at lane 20g+q.
#pragma unroll
        for (int q = 0; q < 4; ++q) {
            const float sd = __shfl(accS[q], g * 20 + q, 64);
            const float nr = sqrtf(fmaxf(sd, 0.f));
            const float denom = fmaxf(nr * na, 1e-8f);
            float cosv = accC[q] / denom;
            float mx = cosv;
#pragma unroll
            for (int o = 1; o < 16; o <<= 1) mx = fmaxf(mx, __shfl_xor(mx, o, 16));
            const float e = __expf(cosv - mx);
            float s = e;
#pragma unroll
            for (int o = 1; o < 16; o <<= 1) s += __shfl_xor(s, o, 16);
            out[(rowbase + g * 4 + q) * NC + c] = e / s;
        }
    }
}

// ======================= fallback path (R3, verbatim behavior) =======================

__global__ __launch_bounds__(1024) void k_accum(
    const float* __restrict__ seq,
    const float* __restrict__ seq1,
    const int* __restrict__ labels,
    const float* __restrict__ a4p,
    float* __restrict__ ws)
{
    __shared__ int lsum[NC * FT];
    __shared__ int lcnt[NC];
    const int tid = threadIdx.x;
    for (int i = tid; i < NC * FT; i += 1024) lsum[i] = 0;
    if (tid < NC) lcnt[tid] = 0;
    __syncthreads();

    const int rr = tid >> 5;
    const int m  = tid & 31;
    const int f0 = m * 8;
    const int mh = m >> 2;
    int off[8];
#pragma unroll
    for (int i = 0; i < 8; ++i) off[i] = (i + mh) & 7;

    float cof[8];
    {
        const float4 c0 = *(const float4*)(ws + WS_COEF + f0);
        const float4 c1 = *(const float4*)(ws + WS_COEF + f0 + 4);
        cof[0]=c0.x; cof[1]=c0.y; cof[2]=c0.z; cof[3]=c0.w;
        cof[4]=c1.x; cof[5]=c1.y; cof[6]=c1.z; cof[7]=c1.w;
    }
    const float a4v = a4p[0];

    for (int row = blockIdx.x * 32 + rr; row < NROWS; row += gridDim.x * 32) {
        const int lab = labels[row];
        const float4 sa  = *(const float4*)(seq  + row * FT + f0);
        const float4 sb  = *(const float4*)(seq  + row * FT + f0 + 4);
        const float4 ta  = *(const float4*)(seq1 + row * FT + f0);
        const float4 tb  = *(const float4*)(seq1 + row * FT + f0 + 4);
        const float s[8]  = {sa.x,sa.y,sa.z,sa.w, sb.x,sb.y,sb.z,sb.w};
        const float t[8]  = {ta.x,ta.y,ta.z,ta.w, tb.x,tb.y,tb.z,tb.w};
        int* base = lsum + lab * FT + f0;
#pragma unroll
        for (int i = 0; i < 8; ++i) {
            float u = cof[i] * s[i];
            float r = (u > 0.f) ? u : (__expf(u) - 1.f);
            atomicAdd(base + off[i], __float2int_rn((r + a4v * t[i]) * FPSCALE));
        }
        if (m == 0) atomicAdd(&lcnt[lab], 1);
    }
    __syncthreads();

    int* gsum = (int*)(ws + WS_SUMS);
    for (int idx = tid; idx < NC * FT; idx += 1024) {
        int p  = idx & 255;
        int mm = p >> 3;
        int r  = p & 7;
        int f  = (p & ~7) | ((r - (mm >> 2)) & 7);
        atomicAdd(gsum + (idx & ~255) + f, lsum[idx]);
    }
    if (tid < NC) atomicAdd((int*)(ws + WS_CNTS) + tid, lcnt[tid]);
}

__global__ void k_final(float* __restrict__ ws)
{
    __shared__ float nacc[NC];
    const int f = threadIdx.x;
    if (f < NC) nacc[f] = 0.f;
    __syncthreads();
    const int* gsum = (const int*)(ws + WS_SUMS);
    const int* gcnt = (const int*)(ws + WS_CNTS);
    unsigned short* aveb = (unsigned short*)(ws + WS_AVEB);
#pragma unroll
    for (int c = 0; c < NC; ++c) {
        float cnt = (float)gcnt[c];
        float a = ((float)gsum[c * FT + f] * FPINV) / fmaxf(cnt, 1.f);
        unsigned short ab = f2bf(a);
        aveb[c * FT + f] = ab;
        float af = bfbits2f(ab);
        atomicAdd(&nacc[c], af * af);
    }
    __syncthreads();
    if (f < NC) ws[WS_NRM + f] = sqrtf(nacc[f]);
}

__global__ __launch_bounds__(256) void k_out(
    const float* __restrict__ seq,
    const float* __restrict__ seq1,
    const float* __restrict__ a4p,
    const float* __restrict__ ws,
    float* __restrict__ out)
{
    __shared__ __align__(16) float scoef[FT];
    const int tid = threadIdx.x;
    for (int i = tid; i < FT; i += 256) scoef[i] = ws[WS_COEF + i];
    __syncthreads();

    const int lane = tid & 63;
    const int wv   = tid >> 6;
    const int c = lane & 15;
    const int g = lane >> 4;

    const unsigned short* aveb = (const unsigned short*)(ws + WS_AVEB);
    bf16x8 bfrag[8];
#pragma unroll
    for (int kc = 0; kc < 8; ++kc)
        bfrag[kc] = *(const bf16x8*)(aveb + c * FT + kc * 32 + g * 8);
    const float na  = ws[WS_NRM + c];
    const float a4v = a4p[0];

    const int ntiles = NROWS / 16;
    for (int tile = blockIdx.x * 4 + wv; tile < ntiles; tile += gridDim.x * 4) {
        const int rowbase = tile * 16;
        const int arow = rowbase + c;
        f32x4 accC = {0.f, 0.f, 0.f, 0.f};
        f32x4 accS = {0.f, 0.f, 0.f, 0.f};
#pragma unroll
        for (int kc = 0; kc < 8; ++kc) {
            const int k0 = kc * 32 + g * 8;
            const float4 sa = *(const float4*)(seq  + arow * FT + k0);
            const float4 sb = *(const float4*)(seq  + arow * FT + k0 + 4);
            const float4 ta = *(const float4*)(seq1 + arow * FT + k0);
            const float4 tb = *(const float4*)(seq1 + arow * FT + k0 + 4);
            const float4 c0 = *(const float4*)(scoef + k0);
            const float4 c1 = *(const float4*)(scoef + k0 + 4);
            const float s[8]  = {sa.x,sa.y,sa.z,sa.w, sb.x,sb.y,sb.z,sb.w};
            const float t[8]  = {ta.x,ta.y,ta.z,ta.w, tb.x,tb.y,tb.z,tb.w};
            const float cf[8] = {c0.x,c0.y,c0.z,c0.w, c1.x,c1.y,c1.z,c1.w};
            bf16x8 afrag;
#pragma unroll
            for (int i = 0; i < 8; ++i) {
                float u = cf[i] * s[i];
                float r = (u > 0.f) ? u : (__expf(u) - 1.f);
                afrag[i] = (short)f2bf(r + a4v * t[i]);
            }
            accC = __builtin_amdgcn_mfma_f32_16x16x32_bf16(afrag, bfrag[kc], accC, 0, 0, 0);
            accS = __builtin_amdgcn_mfma_f32_16x16x32_bf16(afrag, afrag,     accS, 0, 0, 0);
        }
#pragma unroll
        for (int q = 0; q < 4; ++q) {
            const float sd = __shfl(accS[q], g * 20 + q, 64);
            const float nr = sqrtf(fmaxf(sd, 0.f));
            const float denom = fmaxf(nr * na, 1e-8f);
            float cosv = accC[q] / denom;
            float mx = cosv;
#pragma unroll
            for (int o = 1; o < 16; o <<= 1) mx = fmaxf(mx, __shfl_xor(mx, o, 16));
            const float e = __expf(cosv - mx);
            float s = e;
#pragma unroll
            for (int o = 1; o < 16; o <<= 1) s += __shfl_xor(s, o, 16);
            out[(rowbase + g * 4 + q) * NC + c] = e / s;
        }
    }
}

extern "C" void kernel_launch(void* const* d_in, const int* in_sizes, int n_in,
                              void* d_out, int out_size, void* d_ws, size_t ws_size,
                              hipStream_t stream)
{
    const float* seq  = (const float*)d_in[0];
    const float* seq1 = (const float*)d_in[1];
    const int*   lab  = (const int*)d_in[2];
    const float* p1   = (const float*)d_in[3];
    const float* p2   = (const float*)d_in[4];
    const float* p3   = (const float*)d_in[5];
    const float* wwp  = (const float*)d_in[6];
    const float* wwf  = (const float*)d_in[7];
    const float* wdp  = (const float*)d_in[8];
    const float* a4   = (const float*)d_in[9];
    float* ws  = (float*)d_ws;
    float* out = (float*)d_out;

    if (ws_size >= CACHED_NEED_BYTES) {
        // cached path: no global atomics, no memset, bf16 rawret cache
        k_prep   <<<1,    256, 0, stream>>>(p1, p2, p3, wwp, wwf, wdp, ws);
        k_accum_c<<<NBLK, 1024, 0, stream>>>(seq, seq1, lab, a4, ws);
        k_reduce <<<NC,   256, 0, stream>>>(ws);
        k_out_c  <<<1568, 256, 0, stream>>>(ws, out);
    } else {
        // fallback: R3 structure
        hipMemsetAsync((char*)d_ws + WS_SUMS * sizeof(int), 0,
                       (NC * FT + NC) * sizeof(int), stream);
        k_prep <<<1,    256, 0, stream>>>(p1, p2, p3, wwp, wwf, wdp, ws);
        k_accum<<<512, 1024, 0, stream>>>(seq, seq1, lab, a4, ws);
        k_final<<<1,    256, 0, stream>>>(ws);
        k_out  <<<1568, 256, 0, stream>>>(seq, seq1, a4, ws, out);
    }
}

// Round 5
// 270.361 us; speedup vs baseline: 1.4668x; 1.0813x over previous
//
#include <hip/hip_runtime.h>
#include <hip/hip_bf16.h>

#define NROWS 100000
#define FT 256
#define NC 16
#define NBLK 512          // k_accum blocks (cached path)
#define NSL 8             // stage-2 reduce slices
#define SLICE (NBLK / NSL)

// fixed-point scale for class-sum accumulation
#define FPSCALE 1048576.0f      // 2^20
#define FPINV   (1.0f / 1048576.0f)

// ---------------- cached-path ws layout (4-byte words) ----------------
#define CW_AVEB 0                       // 2048 words = 4096 bf16 ave [c][f]
#define CW_NRM  2048                    // 16 floats
#define CW_PCNT 2064                    // NBLK*NC ints
#define CW_ST2C (CW_PCNT + NBLK*NC)     // NSL*NC ints
#define CW_ST2  (CW_ST2C + NSL*NC)      // NSL*NC*FT ints
#define CW_PART (CW_ST2 + NSL*NC*FT)    // NBLK*NC*FT ints
#define CW_RAWB (CW_PART + NBLK*NC*FT)  // NROWS*FT bf16
#define CW_TOTAL (CW_RAWB + (NROWS*FT)/2)
#define CACHED_NEED_BYTES ((size_t)CW_TOTAL * 4)

// ---------------- fallback ws layout (R3, 4-byte words) ----------------
#define WS_COEF 0
#define WS_SUMS 256
#define WS_CNTS 4352
#define WS_AVEB 4368
#define WS_NRM  6416

typedef float f32x4 __attribute__((ext_vector_type(4)));
typedef short bf16x8 __attribute__((ext_vector_type(8)));

static __device__ __forceinline__ float bfbits2f(unsigned int u16) {
    union { unsigned int i; float f; } v; v.i = u16 << 16; return v.f;
}
static __device__ __forceinline__ unsigned short f2bf(float f) {
    union { float f; unsigned int i; } v; v.f = f;
    unsigned int u = v.i;
    u += 0x7fffu + ((u >> 16) & 1u);   // RNE
    return (unsigned short)(u >> 16);
}

// ======================= cached path =======================

// K1c: compute coef in-block, compute rawret, cache as bf16, accumulate
// per-class fixed-point sums in LDS (native ds_add), write block-private
// partials (no global atomics). 32 lanes/row, 8 features/lane,
// row-unrolled x2 for memory-level parallelism.
__global__ __launch_bounds__(512) void k_accum_c(
    const float* __restrict__ seq,
    const float* __restrict__ seq1,
    const int* __restrict__ labels,
    const float* __restrict__ p1,
    const float* __restrict__ p2,
    const float* __restrict__ p3,
    const float* __restrict__ wwp,
    const float* __restrict__ wwf,
    const float* __restrict__ wdp,
    const float* __restrict__ a4p,
    float* __restrict__ ws)
{
    __shared__ int lsum[NC * FT];
    __shared__ int lcnt[NC];
    __shared__ __align__(16) float scoef[FT];
    const int tid = threadIdx.x;
    for (int i = tid; i < NC * FT; i += 512) lsum[i] = 0;
    if (tid < NC) lcnt[tid] = 0;
    if (tid < FT) {
        float z = wwp[0] * p1[tid] + wwp[1] * p2[tid] + wwp[2] * p3[tid];
        float w = (z > 0.f) ? (1.f + z) : __expf(z);   // 1 + elu(z)
        scoef[tid] = wwf[0] * w + wwf[1] * wdp[tid];
    }
    __syncthreads();

    const int rr = tid >> 5;      // row-in-block 0..15
    const int m  = tid & 31;      // lane-in-row
    const int f0 = m * 8;
    const int mh = m >> 2;
    int off[8];
#pragma unroll
    for (int i = 0; i < 8; ++i) off[i] = (i + mh) & 7;

    float cof[8];
    {
        const float4 c0 = *(const float4*)(scoef + f0);
        const float4 c1 = *(const float4*)(scoef + f0 + 4);
        cof[0]=c0.x; cof[1]=c0.y; cof[2]=c0.z; cof[3]=c0.w;
        cof[4]=c1.x; cof[5]=c1.y; cof[6]=c1.z; cof[7]=c1.w;
    }
    const float a4v = a4p[0];
    unsigned int* rawb = (unsigned int*)(ws + CW_RAWB);

    const int stride = NBLK * 16;          // 8192
    for (int rowA = blockIdx.x * 16 + rr; rowA < NROWS; rowA += stride * 2) {
        const int rowBr = rowA + stride;
        const bool vB = rowBr < NROWS;
        const int rowB = vB ? rowBr : rowA;
        // issue all loads first (10 independent requests)
        const int labA = labels[rowA];
        const int labB = labels[rowB];
        const float4 saA = *(const float4*)(seq  + rowA * FT + f0);
        const float4 sbA = *(const float4*)(seq  + rowA * FT + f0 + 4);
        const float4 taA = *(const float4*)(seq1 + rowA * FT + f0);
        const float4 tbA = *(const float4*)(seq1 + rowA * FT + f0 + 4);
        const float4 saB = *(const float4*)(seq  + rowB * FT + f0);
        const float4 sbB = *(const float4*)(seq  + rowB * FT + f0 + 4);
        const float4 taB = *(const float4*)(seq1 + rowB * FT + f0);
        const float4 tbB = *(const float4*)(seq1 + rowB * FT + f0 + 4);

        const float sA[8] = {saA.x,saA.y,saA.z,saA.w, sbA.x,sbA.y,sbA.z,sbA.w};
        const float tA[8] = {taA.x,taA.y,taA.z,taA.w, tbA.x,tbA.y,tbA.z,tbA.w};
        const float sB[8] = {saB.x,saB.y,saB.z,saB.w, sbB.x,sbB.y,sbB.z,sbB.w};
        const float tB[8] = {taB.x,taB.y,taB.z,taB.w, tbB.x,tbB.y,tbB.z,tbB.w};

        int* baseA = lsum + labA * FT + f0;
        unsigned short vbA[8];
#pragma unroll
        for (int i = 0; i < 8; ++i) {
            float u = cof[i] * sA[i];
            float r = (u > 0.f) ? u : (__expf(u) - 1.f);   // elu
            float v = r + a4v * tA[i];
            vbA[i] = f2bf(v);
            atomicAdd(baseA + off[i], __float2int_rn(v * FPSCALE));
        }
        uint4 pkA;
        pkA.x = (unsigned int)vbA[0] | ((unsigned int)vbA[1] << 16);
        pkA.y = (unsigned int)vbA[2] | ((unsigned int)vbA[3] << 16);
        pkA.z = (unsigned int)vbA[4] | ((unsigned int)vbA[5] << 16);
        pkA.w = (unsigned int)vbA[6] | ((unsigned int)vbA[7] << 16);
        *(uint4*)(rawb + (rowA * FT + f0) / 2) = pkA;
        if (m == 0) atomicAdd(&lcnt[labA], 1);

        int* baseB = lsum + labB * FT + f0;
        unsigned short vbB[8];
        float vv[8];
#pragma unroll
        for (int i = 0; i < 8; ++i) {
            float u = cof[i] * sB[i];
            float r = (u > 0.f) ? u : (__expf(u) - 1.f);
            vv[i] = r + a4v * tB[i];
            vbB[i] = f2bf(vv[i]);
        }
        if (vB) {
#pragma unroll
            for (int i = 0; i < 8; ++i)
                atomicAdd(baseB + off[i], __float2int_rn(vv[i] * FPSCALE));
            uint4 pkB;
            pkB.x = (unsigned int)vbB[0] | ((unsigned int)vbB[1] << 16);
            pkB.y = (unsigned int)vbB[2] | ((unsigned int)vbB[3] << 16);
            pkB.z = (unsigned int)vbB[4] | ((unsigned int)vbB[5] << 16);
            pkB.w = (unsigned int)vbB[6] | ((unsigned int)vbB[7] << 16);
            *(uint4*)(rawb + (rowB * FT + f0) / 2) = pkB;
            if (m == 0) atomicAdd(&lcnt[labB], 1);
        }
    }
    __syncthreads();

    // flush block-private partials (unswizzle): pos p=8m+r holds
    // feature f=8m+((r-(m>>2))&7). partial layout [block][c][f].
    int* gpart = (int*)(ws + CW_PART) + blockIdx.x * (NC * FT);
    for (int idx = tid; idx < NC * FT; idx += 512) {
        int p  = idx & 255;
        int mm = p >> 3;
        int r  = p & 7;
        int f  = (p & ~7) | ((r - (mm >> 2)) & 7);
        gpart[(idx & ~255) + f] = lsum[idx];
    }
    if (tid < NC) ((int*)(ws + CW_PCNT))[blockIdx.x * NC + tid] = lcnt[tid];
}

// K1.5c stage 1: 128 blocks = (class, slice); sum 64 partials + counts
__global__ __launch_bounds__(256) void k_reduce1(float* __restrict__ ws)
{
    const int c = blockIdx.x >> 3;   // class
    const int r = blockIdx.x & 7;    // slice
    const int f = threadIdx.x;
    const int p0 = r * SLICE;
    const int* gpart = (const int*)(ws + CW_PART);
    int acc = 0;
#pragma unroll 8
    for (int p = 0; p < SLICE; ++p)
        acc += gpart[(p0 + p) * (NC * FT) + c * FT + f];
    ((int*)(ws + CW_ST2))[(r * NC + c) * FT + f] = acc;

    if (f < SLICE) {
        int cc = ((const int*)(ws + CW_PCNT))[(p0 + f) * NC + c];
#pragma unroll
        for (int o = 32; o > 0; o >>= 1) cc += __shfl_down(cc, o, 64);
        if (f == 0) ((int*)(ws + CW_ST2C))[r * NC + c] = cc;
    }
}

// K1.5c stage 2: 16 blocks (one per class): 8-way sum -> ave bf16 + norm
__global__ __launch_bounds__(256) void k_reduce2(float* __restrict__ ws)
{
    __shared__ float red[256];
    const int c = blockIdx.x;
    const int f = threadIdx.x;
    const int* st2  = (const int*)(ws + CW_ST2);
    const int* st2c = (const int*)(ws + CW_ST2C);
    long long isum = 0;
    int cnt = 0;
#pragma unroll
    for (int s = 0; s < NSL; ++s) {
        isum += (long long)st2[(s * NC + c) * FT + f];
        cnt  += st2c[s * NC + c];
    }
    float a = ((float)isum * FPINV) / fmaxf((float)cnt, 1.f);
    unsigned short ab = f2bf(a);
    ((unsigned short*)(ws + CW_AVEB))[c * FT + f] = ab;
    float af = bfbits2f(ab);

    red[f] = af * af;
    __syncthreads();
#pragma unroll
    for (int s = 128; s > 0; s >>= 1) {
        if (f < s) red[f] += red[f + s];
        __syncthreads();
    }
    if (f == 0) ws[CW_NRM + c] = sqrtf(red[0]);
}

// K2c: per 16-row tile, load cached bf16 rawret fragments,
//   accC += A . aveT ; accS += A . A^T (diag = self-dots)
// then cosine + softmax via width-16 shuffles.
__global__ __launch_bounds__(256) void k_out_c(
    const float* __restrict__ ws,
    float* __restrict__ out)
{
    const int tid = threadIdx.x;
    const int lane = tid & 63;
    const int wv   = tid >> 6;
    const int c = lane & 15;   // class (B col) == A row index m
    const int g = lane >> 4;   // k-quad

    const unsigned short* aveb = (const unsigned short*)(ws + CW_AVEB);
    const unsigned short* rawb = (const unsigned short*)(ws + CW_RAWB);
    bf16x8 bfrag[8];
#pragma unroll
    for (int kc = 0; kc < 8; ++kc)
        bfrag[kc] = *(const bf16x8*)(aveb + c * FT + kc * 32 + g * 8);
    const float na = ws[CW_NRM + c];

    const int ntiles = NROWS / 16;   // 6250 exact
    for (int tile = blockIdx.x * 4 + wv; tile < ntiles; tile += gridDim.x * 4) {
        const int rowbase = tile * 16;
        const int arow = rowbase + c;     // A row m = lane&15
        f32x4 accC = {0.f, 0.f, 0.f, 0.f};
        f32x4 accS = {0.f, 0.f, 0.f, 0.f};
#pragma unroll
        for (int kc = 0; kc < 8; ++kc) {
            bf16x8 afrag = *(const bf16x8*)(rawb + arow * FT + kc * 32 + g * 8);
            accC = __builtin_amdgcn_mfma_f32_16x16x32_bf16(afrag, bfrag[kc], accC, 0, 0, 0);
            accS = __builtin_amdgcn_mfma_f32_16x16x32_bf16(afrag, afrag,     accS, 0, 0, 0);
        }
        // C/D layout: col=lane&15, row=g*4+reg; self-dot of row r=4g+q at lane 20g+q.
#pragma unroll
        for (int q = 0; q < 4; ++q) {
            const float sd = __shfl(accS[q], g * 20 + q, 64);
            const float nr = sqrtf(fmaxf(sd, 0.f));
            const float denom = fmaxf(nr * na, 1e-8f);
            float cosv = accC[q] / denom;
            float mx = cosv;
#pragma unroll
            for (int o = 1; o < 16; o <<= 1) mx = fmaxf(mx, __shfl_xor(mx, o, 16));
            const float e = __expf(cosv - mx);
            float s = e;
#pragma unroll
            for (int o = 1; o < 16; o <<= 1) s += __shfl_xor(s, o, 16);
            out[(rowbase + g * 4 + q) * NC + c] = e / s;
        }
    }
}

// ======================= fallback path (R3, verbatim behavior) =======================

__global__ void k_prep(const float* __restrict__ p1,
                       const float* __restrict__ p2,
                       const float* __restrict__ p3,
                       const float* __restrict__ wwp,
                       const float* __restrict__ wwf,
                       const float* __restrict__ wdp,
                       float* __restrict__ ws)
{
    int f = threadIdx.x;
    float z = wwp[0] * p1[f] + wwp[1] * p2[f] + wwp[2] * p3[f];
    float weight = (z > 0.f) ? (1.f + z) : __expf(z);
    ws[WS_COEF + f] = wwf[0] * weight + wwf[1] * wdp[f];
}

__global__ __launch_bounds__(1024) void k_accum(
    const float* __restrict__ seq,
    const float* __restrict__ seq1,
    const int* __restrict__ labels,
    const float* __restrict__ a4p,
    float* __restrict__ ws)
{
    __shared__ int lsum[NC * FT];
    __shared__ int lcnt[NC];
    const int tid = threadIdx.x;
    for (int i = tid; i < NC * FT; i += 1024) lsum[i] = 0;
    if (tid < NC) lcnt[tid] = 0;
    __syncthreads();

    const int rr = tid >> 5;
    const int m  = tid & 31;
    const int f0 = m * 8;
    const int mh = m >> 2;
    int off[8];
#pragma unroll
    for (int i = 0; i < 8; ++i) off[i] = (i + mh) & 7;

    float cof[8];
    {
        const float4 c0 = *(const float4*)(ws + WS_COEF + f0);
        const float4 c1 = *(const float4*)(ws + WS_COEF + f0 + 4);
        cof[0]=c0.x; cof[1]=c0.y; cof[2]=c0.z; cof[3]=c0.w;
        cof[4]=c1.x; cof[5]=c1.y; cof[6]=c1.z; cof[7]=c1.w;
    }
    const float a4v = a4p[0];

    for (int row = blockIdx.x * 32 + rr; row < NROWS; row += gridDim.x * 32) {
        const int lab = labels[row];
        const float4 sa  = *(const float4*)(seq  + row * FT + f0);
        const float4 sb  = *(const float4*)(seq  + row * FT + f0 + 4);
        const float4 ta  = *(const float4*)(seq1 + row * FT + f0);
        const float4 tb  = *(const float4*)(seq1 + row * FT + f0 + 4);
        const float s[8]  = {sa.x,sa.y,sa.z,sa.w, sb.x,sb.y,sb.z,sb.w};
        const float t[8]  = {ta.x,ta.y,ta.z,ta.w, tb.x,tb.y,tb.z,tb.w};
        int* base = lsum + lab * FT + f0;
#pragma unroll
        for (int i = 0; i < 8; ++i) {
            float u = cof[i] * s[i];
            float r = (u > 0.f) ? u : (__expf(u) - 1.f);
            atomicAdd(base + off[i], __float2int_rn((r + a4v * t[i]) * FPSCALE));
        }
        if (m == 0) atomicAdd(&lcnt[lab], 1);
    }
    __syncthreads();

    int* gsum = (int*)(ws + WS_SUMS);
    for (int idx = tid; idx < NC * FT; idx += 1024) {
        int p  = idx & 255;
        int mm = p >> 3;
        int r  = p & 7;
        int f  = (p & ~7) | ((r - (mm >> 2)) & 7);
        atomicAdd(gsum + (idx & ~255) + f, lsum[idx]);
    }
    if (tid < NC) atomicAdd((int*)(ws + WS_CNTS) + tid, lcnt[tid]);
}

__global__ void k_final(float* __restrict__ ws)
{
    __shared__ float nacc[NC];
    const int f = threadIdx.x;
    if (f < NC) nacc[f] = 0.f;
    __syncthreads();
    const int* gsum = (const int*)(ws + WS_SUMS);
    const int* gcnt = (const int*)(ws + WS_CNTS);
    unsigned short* aveb = (unsigned short*)(ws + WS_AVEB);
#pragma unroll
    for (int c = 0; c < NC; ++c) {
        float cnt = (float)gcnt[c];
        float a = ((float)gsum[c * FT + f] * FPINV) / fmaxf(cnt, 1.f);
        unsigned short ab = f2bf(a);
        aveb[c * FT + f] = ab;
        float af = bfbits2f(ab);
        atomicAdd(&nacc[c], af * af);
    }
    __syncthreads();
    if (f < NC) ws[WS_NRM + f] = sqrtf(nacc[f]);
}

__global__ __launch_bounds__(256) void k_out(
    const float* __restrict__ seq,
    const float* __restrict__ seq1,
    const float* __restrict__ a4p,
    const float* __restrict__ ws,
    float* __restrict__ out)
{
    __shared__ __align__(16) float scoef[FT];
    const int tid = threadIdx.x;
    for (int i = tid; i < FT; i += 256) scoef[i] = ws[WS_COEF + i];
    __syncthreads();

    const int lane = tid & 63;
    const int wv   = tid >> 6;
    const int c = lane & 15;
    const int g = lane >> 4;

    const unsigned short* aveb = (const unsigned short*)(ws + WS_AVEB);
    bf16x8 bfrag[8];
#pragma unroll
    for (int kc = 0; kc < 8; ++kc)
        bfrag[kc] = *(const bf16x8*)(aveb + c * FT + kc * 32 + g * 8);
    const float na  = ws[WS_NRM + c];
    const float a4v = a4p[0];

    const int ntiles = NROWS / 16;
    for (int tile = blockIdx.x * 4 + wv; tile < ntiles; tile += gridDim.x * 4) {
        const int rowbase = tile * 16;
        const int arow = rowbase + c;
        f32x4 accC = {0.f, 0.f, 0.f, 0.f};
        f32x4 accS = {0.f, 0.f, 0.f, 0.f};
#pragma unroll
        for (int kc = 0; kc < 8; ++kc) {
            const int k0 = kc * 32 + g * 8;
            const float4 sa = *(const float4*)(seq  + arow * FT + k0);
            const float4 sb = *(const float4*)(seq  + arow * FT + k0 + 4);
            const float4 ta = *(const float4*)(seq1 + arow * FT + k0);
            const float4 tb = *(const float4*)(seq1 + arow * FT + k0 + 4);
            const float4 c0 = *(const float4*)(scoef + k0);
            const float4 c1 = *(const float4*)(scoef + k0 + 4);
            const float s[8]  = {sa.x,sa.y,sa.z,sa.w, sb.x,sb.y,sb.z,sb.w};
            const float t[8]  = {ta.x,ta.y,ta.z,ta.w, tb.x,tb.y,tb.z,tb.w};
            const float cf[8] = {c0.x,c0.y,c0.z,c0.w, c1.x,c1.y,c1.z,c1.w};
            bf16x8 afrag;
#pragma unroll
            for (int i = 0; i < 8; ++i) {
                float u = cf[i] * s[i];
                float r = (u > 0.f) ? u : (__expf(u) - 1.f);
                afrag[i] = (short)f2bf(r + a4v * t[i]);
            }
            accC = __builtin_amdgcn_mfma_f32_16x16x32_bf16(afrag, bfrag[kc], accC, 0, 0, 0);
            accS = __builtin_amdgcn_mfma_f32_16x16x32_bf16(afrag, afrag,     accS, 0, 0, 0);
        }
#pragma unroll
        for (int q = 0; q < 4; ++q) {
            const float sd = __shfl(accS[q], g * 20 + q, 64);
            const float nr = sqrtf(fmaxf(sd, 0.f));
            const float denom = fmaxf(nr * na, 1e-8f);
            float cosv = accC[q] / denom;
            float mx = cosv;
#pragma unroll
            for (int o = 1; o < 16; o <<= 1) mx = fmaxf(mx, __shfl_xor(mx, o, 16));
            const float e = __expf(cosv - mx);
            float s = e;
#pragma unroll
            for (int o = 1; o < 16; o <<= 1) s += __shfl_xor(s, o, 16);
            out[(rowbase + g * 4 + q) * NC + c] = e / s;
        }
    }
}

extern "C" void kernel_launch(void* const* d_in, const int* in_sizes, int n_in,
                              void* d_out, int out_size, void* d_ws, size_t ws_size,
                              hipStream_t stream)
{
    const float* seq  = (const float*)d_in[0];
    const float* seq1 = (const float*)d_in[1];
    const int*   lab  = (const int*)d_in[2];
    const float* p1   = (const float*)d_in[3];
    const float* p2   = (const float*)d_in[4];
    const float* p3   = (const float*)d_in[5];
    const float* wwp  = (const float*)d_in[6];
    const float* wwf  = (const float*)d_in[7];
    const float* wdp  = (const float*)d_in[8];
    const float* a4   = (const float*)d_in[9];
    float* ws  = (float*)d_ws;
    float* out = (float*)d_out;

    if (ws_size >= CACHED_NEED_BYTES) {
        // cached path: no global atomics, no memset, bf16 rawret cache
        k_accum_c<<<NBLK,     512, 0, stream>>>(seq, seq1, lab, p1, p2, p3,
                                                wwp, wwf, wdp, a4, ws);
        k_reduce1<<<NC * NSL, 256, 0, stream>>>(ws);
        k_reduce2<<<NC,       256, 0, stream>>>(ws);
        k_out_c  <<<1568,     256, 0, stream>>>(ws, out);
    } else {
        // fallback: R3 structure
        hipMemsetAsync((char*)d_ws + WS_SUMS * sizeof(int), 0,
                       (NC * FT + NC) * sizeof(int), stream);
        k_prep <<<1,    256, 0, stream>>>(p1, p2, p3, wwp, wwf, wdp, ws);
        k_accum<<<512, 1024, 0, stream>>>(seq, seq1, lab, a4, ws);
        k_final<<<1,    256, 0, stream>>>(ws);
        k_out  <<<1568, 256, 0, stream>>>(seq, seq1, a4, ws, out);
    }
}